// Round 2
// baseline (1567.256 us; speedup 1.0000x reference)
//
#include <hip/hip_runtime.h>

// Exphormer attention, fp32.
// out[dst] += V[src] * exp(clip(sum_d K[src,h,d]*Q[dst,h,d]/4 * Ee[e,h,d], ±5))
// Ee = edge_attr @ We^T + be

// ---------------- Kernel 1: fused Q/K/V projection ----------------
__global__ __launch_bounds__(256) void proj_kernel(
    const float* __restrict__ x,
    const float* __restrict__ Wq, const float* __restrict__ bq,
    const float* __restrict__ Wk, const float* __restrict__ bk,
    const float* __restrict__ Wv, const float* __restrict__ bv,
    float* __restrict__ Q, float* __restrict__ K, float* __restrict__ V,
    int n)
{
    __shared__ float WqT[64 * 65];
    __shared__ float WkT[64 * 65];
    __shared__ float WvT[64 * 65];
    __shared__ float xs[4][4][64];

    const int tid  = threadIdx.x;
    const int wave = tid >> 6;
    const int lane = tid & 63;

    #pragma unroll
    for (int k = 0; k < 16; ++k) {
        int idx = tid + k * 256;
        int j = idx >> 6, i = idx & 63;
        WqT[i * 65 + j] = Wq[idx];
        WkT[i * 65 + j] = Wk[idx];
        WvT[i * 65 + j] = Wv[idx];
    }
    const float bqv = bq[lane];
    const float bkv = bk[lane];
    const float bvv = bv[lane];
    __syncthreads();

    for (int blockbase = blockIdx.x * 16; blockbase < n;
         blockbase += gridDim.x * 16) {
        int base = blockbase + wave * 4;
        #pragma unroll
        for (int j = 0; j < 4; ++j) {
            int node = base + j;
            xs[wave][j][lane] = (node < n) ? x[node * 64 + lane] : 0.f;
        }
        __syncthreads();

        float accq[4], acck[4], accv[4];
        #pragma unroll
        for (int j = 0; j < 4; ++j) { accq[j] = bqv; acck[j] = bkv; accv[j] = bvv; }

        #pragma unroll
        for (int f = 0; f < 16; ++f) {
            float wq[4], wk[4], wv[4];
            #pragma unroll
            for (int u = 0; u < 4; ++u) {
                int i = 4 * f + u;
                wq[u] = WqT[i * 65 + lane];
                wk[u] = WkT[i * 65 + lane];
                wv[u] = WvT[i * 65 + lane];
            }
            #pragma unroll
            for (int j = 0; j < 4; ++j) {
                float4 xv = *reinterpret_cast<const float4*>(&xs[wave][j][4 * f]);
                accq[j] = fmaf(xv.x, wq[0], accq[j]);
                accq[j] = fmaf(xv.y, wq[1], accq[j]);
                accq[j] = fmaf(xv.z, wq[2], accq[j]);
                accq[j] = fmaf(xv.w, wq[3], accq[j]);
                acck[j] = fmaf(xv.x, wk[0], acck[j]);
                acck[j] = fmaf(xv.y, wk[1], acck[j]);
                acck[j] = fmaf(xv.z, wk[2], acck[j]);
                acck[j] = fmaf(xv.w, wk[3], acck[j]);
                accv[j] = fmaf(xv.x, wv[0], accv[j]);
                accv[j] = fmaf(xv.y, wv[1], accv[j]);
                accv[j] = fmaf(xv.z, wv[2], accv[j]);
                accv[j] = fmaf(xv.w, wv[3], accv[j]);
            }
        }

        #pragma unroll
        for (int j = 0; j < 4; ++j) {
            int node = base + j;
            if (node < n) {
                Q[node * 64 + lane] = accq[j];
                K[node * 64 + lane] = acck[j];
                V[node * 64 + lane] = accv[j];
            }
        }
        __syncthreads();
    }
}

// ---------------- Kernel 2: per-edge attention + scatter ----------------
// block 256 = 4 independent waves (NO block barriers in the loop).
// Each wave: 4 edges per iteration.
//   - We held in LDS as float4 chunks ws4[f][d] = We[d][4f..4f+3]
//     read ws4[f][lane]: 16 lanes x 16B contiguous per phase -> conflict-free
//   - ea rows staged per-wave in LDS, read back as uniform broadcast float4
//   - matvec amortizes each We chunk across the 4 staged edges
#define EPW 4

__global__ __launch_bounds__(256) void edge_kernel(
    const float* __restrict__ ea, const int* __restrict__ ei,
    const float* __restrict__ Q, const float* __restrict__ K,
    const float* __restrict__ V,
    const float* __restrict__ We, const float* __restrict__ be,
    float* __restrict__ out, int EG)
{
    __shared__ float4 ws4[16][64];          // 16 KB: We chunked by 4 cols
    __shared__ float4 eas[4][EPW][16];      // 4 KB: per-wave ea staging

    const int tid  = threadIdx.x;
    const int wave = tid >> 6;
    const int lane = tid & 63;

    {   // stage We once per block
        int d = tid & 63;
        #pragma unroll
        for (int f = tid >> 6; f < 16; f += 4)
            ws4[f][d] = *reinterpret_cast<const float4*>(&We[d * 64 + 4 * f]);
    }
    const float bias = be[lane];
    __syncthreads();   // only barrier: protects ws4 (read-only afterwards)

    const int stride = gridDim.x * 4 * EPW;
    for (int base = (blockIdx.x * 4 + wave) * EPW; base < EG; base += stride) {
        // lane covers edge base+(lane>>4), cols 4*(lane&15).. (+3): 1 KB coalesced
        const int e_l = base + (lane >> 4);
        float4 eav = make_float4(0.f, 0.f, 0.f, 0.f);
        if (e_l < EG)
            eav = *reinterpret_cast<const float4*>(
                      &ea[(size_t)e_l * 64 + (lane & 15) * 4]);
        eas[wave][lane >> 4][lane & 15] = eav;
        __builtin_amdgcn_wave_barrier();  // keep write before reads; lgkmcnt by compiler

        float acc[EPW];
        #pragma unroll
        for (int e = 0; e < EPW; ++e) acc[e] = bias;

        #pragma unroll
        for (int f = 0; f < 16; ++f) {
            float4 wv = ws4[f][lane];
            #pragma unroll
            for (int e = 0; e < EPW; ++e) {
                float4 xv = eas[wave][e][f];   // uniform addr -> LDS broadcast
                acc[e] = fmaf(xv.x, wv.x, acc[e]);
                acc[e] = fmaf(xv.y, wv.y, acc[e]);
                acc[e] = fmaf(xv.z, wv.z, acc[e]);
                acc[e] = fmaf(xv.w, wv.w, acc[e]);
            }
        }

        #pragma unroll
        for (int e = 0; e < EPW; ++e) {
            const int eg = base + e;
            if (eg < EG) {
                const int src = ei[eg];
                const int dst = ei[EG + eg];
                float kv = K[(size_t)src * 64 + lane];
                float qv = Q[(size_t)dst * 64 + lane];
                float t  = kv * qv * 0.25f * acc[e];
                t += __shfl_xor(t, 1);
                t += __shfl_xor(t, 2);
                t += __shfl_xor(t, 4);
                t += __shfl_xor(t, 8);
                t = fminf(fmaxf(t, -5.f), 5.f);
                float s = __expf(t);
                float m = V[(size_t)src * 64 + lane] * s;
                atomicAdd(&out[(size_t)dst * 64 + lane], m);
            }
        }
        __builtin_amdgcn_wave_barrier();  // eas reuse next iteration
    }
}

extern "C" void kernel_launch(void* const* d_in, const int* in_sizes, int n_in,
                              void* d_out, int out_size, void* d_ws, size_t ws_size,
                              hipStream_t stream) {
    const float* x   = (const float*)d_in[0];
    const float* ea  = (const float*)d_in[1];
    const int*   ei  = (const int*)d_in[2];
    const float* Wq  = (const float*)d_in[3];
    const float* bq  = (const float*)d_in[4];
    const float* Wk  = (const float*)d_in[5];
    const float* bk  = (const float*)d_in[6];
    const float* We  = (const float*)d_in[7];
    const float* be  = (const float*)d_in[8];
    const float* Wv  = (const float*)d_in[9];
    const float* bv  = (const float*)d_in[10];
    float* out = (float*)d_out;

    const int n  = in_sizes[0] / 64;   // 50000
    const int EG = in_sizes[1] / 64;   // 1600000

    float* Q = (float*)d_ws;
    float* K = Q + (size_t)n * 64;
    float* V = K + (size_t)n * 64;

    hipMemsetAsync(d_out, 0, (size_t)out_size * sizeof(float), stream);

    const int projGrid = (n + 15) / 16;
    proj_kernel<<<projGrid, 256, 0, stream>>>(x, Wq, bq, Wk, bk, Wv, bv,
                                              Q, K, V, n);

    const int edgeGrid = 2048;
    edge_kernel<<<edgeGrid, 256, 0, stream>>>(ea, ei, Q, K, V, We, be,
                                              out, EG);
}

// Round 3
// 626.546 us; speedup vs baseline: 2.5014x; 2.5014x over previous
//
#include <hip/hip_runtime.h>

// Exphormer attention, fp32.
// out[dst] += V[src] * exp(clip(sum_d K[src,h,d]*Q[dst,h,d]/4 * Ee[e,h,d], ±5))
// Ee = edge_attr @ We^T + be

// ---------------- Kernel 1: fused Q/K/V projection ----------------
__global__ __launch_bounds__(256) void proj_kernel(
    const float* __restrict__ x,
    const float* __restrict__ Wq, const float* __restrict__ bq,
    const float* __restrict__ Wk, const float* __restrict__ bk,
    const float* __restrict__ Wv, const float* __restrict__ bv,
    float* __restrict__ Q, float* __restrict__ K, float* __restrict__ V,
    int n)
{
    __shared__ float WqT[64 * 65];
    __shared__ float WkT[64 * 65];
    __shared__ float WvT[64 * 65];
    __shared__ float xs[4][4][64];

    const int tid  = threadIdx.x;
    const int wave = tid >> 6;
    const int lane = tid & 63;

    #pragma unroll
    for (int k = 0; k < 16; ++k) {
        int idx = tid + k * 256;
        int j = idx >> 6, i = idx & 63;
        WqT[i * 65 + j] = Wq[idx];
        WkT[i * 65 + j] = Wk[idx];
        WvT[i * 65 + j] = Wv[idx];
    }
    const float bqv = bq[lane];
    const float bkv = bk[lane];
    const float bvv = bv[lane];
    __syncthreads();

    for (int blockbase = blockIdx.x * 16; blockbase < n;
         blockbase += gridDim.x * 16) {
        int base = blockbase + wave * 4;
        #pragma unroll
        for (int j = 0; j < 4; ++j) {
            int node = base + j;
            xs[wave][j][lane] = (node < n) ? x[node * 64 + lane] : 0.f;
        }
        __syncthreads();

        float accq[4], acck[4], accv[4];
        #pragma unroll
        for (int j = 0; j < 4; ++j) { accq[j] = bqv; acck[j] = bkv; accv[j] = bvv; }

        #pragma unroll
        for (int f = 0; f < 16; ++f) {
            float wq[4], wk[4], wv[4];
            #pragma unroll
            for (int u = 0; u < 4; ++u) {
                int i = 4 * f + u;
                wq[u] = WqT[i * 65 + lane];
                wk[u] = WkT[i * 65 + lane];
                wv[u] = WvT[i * 65 + lane];
            }
            #pragma unroll
            for (int j = 0; j < 4; ++j) {
                float4 xv = *reinterpret_cast<const float4*>(&xs[wave][j][4 * f]);
                accq[j] = fmaf(xv.x, wq[0], accq[j]);
                accq[j] = fmaf(xv.y, wq[1], accq[j]);
                accq[j] = fmaf(xv.z, wq[2], accq[j]);
                accq[j] = fmaf(xv.w, wq[3], accq[j]);
                acck[j] = fmaf(xv.x, wk[0], acck[j]);
                acck[j] = fmaf(xv.y, wk[1], acck[j]);
                acck[j] = fmaf(xv.z, wk[2], acck[j]);
                acck[j] = fmaf(xv.w, wk[3], acck[j]);
                accv[j] = fmaf(xv.x, wv[0], accv[j]);
                accv[j] = fmaf(xv.y, wv[1], accv[j]);
                accv[j] = fmaf(xv.z, wv[2], accv[j]);
                accv[j] = fmaf(xv.w, wv[3], accv[j]);
            }
        }

        #pragma unroll
        for (int j = 0; j < 4; ++j) {
            int node = base + j;
            if (node < n) {
                Q[node * 64 + lane] = accq[j];
                K[node * 64 + lane] = acck[j];
                V[node * 64 + lane] = accv[j];
            }
        }
        __syncthreads();
    }
}

// ---------------- Kernel 2: per-edge attention + scatter ----------------
// block 256 = 4 independent waves, NO block barriers in the loop.
// 1 edge per wave per iteration (low VGPR state -> high occupancy).
// We row for output dim `lane` held in 16 float4 REGISTERS (loaded once;
// __launch_bounds__(256,4) gives a 128-VGPR budget so the compiler keeps
// them instead of re-loading per edge, which is what killed round 1).
// ea row staged wave-private in LDS, read back as uniform float4 broadcasts.
// Edge-uniform values (e, src, dst) forced scalar via readfirstlane ->
// ei loads become s_load, gather/atomic bases are SGPRs.
__global__ __launch_bounds__(256, 4) void edge_kernel(
    const float* __restrict__ ea, const int* __restrict__ ei,
    const float* __restrict__ Q, const float* __restrict__ K,
    const float* __restrict__ V,
    const float* __restrict__ We, const float* __restrict__ be,
    float* __restrict__ out, int EG)
{
    __shared__ float eas[4][64];     // 1 KB: per-wave ea staging

    const int tid  = threadIdx.x;
    const int wave = __builtin_amdgcn_readfirstlane(tid >> 6);
    const int lane = tid & 63;

    // We row -> 16 float4 in registers, loaded ONCE
    float4 w[16];
    const float4* wrow = reinterpret_cast<const float4*>(We + (size_t)lane * 64);
    #pragma unroll
    for (int f = 0; f < 16; ++f) w[f] = wrow[f];
    const float bias = be[lane];

    const int stride = gridDim.x * 4;          // waves in grid
    const int wbase  = blockIdx.x * 4 + wave;  // SGPR

    for (int e = wbase; e < EG; e += stride) { // e stays scalar
        const int src = ei[e];                 // wave-uniform -> s_load
        const int dst = ei[EG + e];

        // stage ea row: 64 lanes x 4B = 256B coalesced
        eas[wave][lane] = ea[(size_t)e * 64 + lane];
        __builtin_amdgcn_wave_barrier();       // order write before reads

        // Ee[lane] = be[lane] + sum_i ea[i] * We[lane,i]
        float acc = bias;
        const float4* eas4 = reinterpret_cast<const float4*>(eas[wave]);
        #pragma unroll
        for (int f = 0; f < 16; ++f) {
            float4 xv = eas4[f];               // uniform addr -> LDS broadcast
            acc = fmaf(xv.x, w[f].x, acc);
            acc = fmaf(xv.y, w[f].y, acc);
            acc = fmaf(xv.z, w[f].z, acc);
            acc = fmaf(xv.w, w[f].w, acc);
        }

        // per-lane partial score, reduce over the 16-lane head group
        float kv = K[(size_t)src * 64 + lane];
        float qv = Q[(size_t)dst * 64 + lane];
        float t  = kv * qv * 0.25f * acc;
        t += __shfl_xor(t, 1);
        t += __shfl_xor(t, 2);
        t += __shfl_xor(t, 4);
        t += __shfl_xor(t, 8);
        t = fminf(fmaxf(t, -5.f), 5.f);
        float s = __expf(t);
        float m = V[(size_t)src * 64 + lane] * s;
        atomicAdd(&out[(size_t)dst * 64 + lane], m);

        __builtin_amdgcn_wave_barrier();       // eas reuse next iteration
    }
}

extern "C" void kernel_launch(void* const* d_in, const int* in_sizes, int n_in,
                              void* d_out, int out_size, void* d_ws, size_t ws_size,
                              hipStream_t stream) {
    const float* x   = (const float*)d_in[0];
    const float* ea  = (const float*)d_in[1];
    const int*   ei  = (const int*)d_in[2];
    const float* Wq  = (const float*)d_in[3];
    const float* bq  = (const float*)d_in[4];
    const float* Wk  = (const float*)d_in[5];
    const float* bk  = (const float*)d_in[6];
    const float* We  = (const float*)d_in[7];
    const float* be  = (const float*)d_in[8];
    const float* Wv  = (const float*)d_in[9];
    const float* bv  = (const float*)d_in[10];
    float* out = (float*)d_out;

    const int n  = in_sizes[0] / 64;   // 50000
    const int EG = in_sizes[1] / 64;   // 1600000

    float* Q = (float*)d_ws;
    float* K = Q + (size_t)n * 64;
    float* V = K + (size_t)n * 64;

    hipMemsetAsync(d_out, 0, (size_t)out_size * sizeof(float), stream);

    const int projGrid = (n + 15) / 16;
    proj_kernel<<<projGrid, 256, 0, stream>>>(x, Wq, bq, Wk, bk, Wv, bv,
                                              Q, K, V, n);

    const int edgeGrid = 4096;
    edge_kernel<<<edgeGrid, 256, 0, stream>>>(ea, ei, Q, K, V, We, be,
                                              out, EG);
}

// Round 4
// 485.351 us; speedup vs baseline: 3.2291x; 1.2909x over previous
//
#include <hip/hip_runtime.h>

// Exphormer attention, fp32.
// out[dst] += V[src] * exp(clip(sum_d K[src,h,d]*Q[dst,h,d]/4 * Ee[e,h,d], ±5))
// Ee = edge_attr @ We^T + be

// ---------------- Kernel 1: fused Q/K/V projection ----------------
__global__ __launch_bounds__(256) void proj_kernel(
    const float* __restrict__ x,
    const float* __restrict__ Wq, const float* __restrict__ bq,
    const float* __restrict__ Wk, const float* __restrict__ bk,
    const float* __restrict__ Wv, const float* __restrict__ bv,
    float* __restrict__ Q, float* __restrict__ K, float* __restrict__ V,
    int n)
{
    __shared__ float WqT[64 * 65];
    __shared__ float WkT[64 * 65];
    __shared__ float WvT[64 * 65];
    __shared__ float xs[4][4][64];

    const int tid  = threadIdx.x;
    const int wave = tid >> 6;
    const int lane = tid & 63;

    #pragma unroll
    for (int k = 0; k < 16; ++k) {
        int idx = tid + k * 256;
        int j = idx >> 6, i = idx & 63;
        WqT[i * 65 + j] = Wq[idx];
        WkT[i * 65 + j] = Wk[idx];
        WvT[i * 65 + j] = Wv[idx];
    }
    const float bqv = bq[lane];
    const float bkv = bk[lane];
    const float bvv = bv[lane];
    __syncthreads();

    for (int blockbase = blockIdx.x * 16; blockbase < n;
         blockbase += gridDim.x * 16) {
        int base = blockbase + wave * 4;
        #pragma unroll
        for (int j = 0; j < 4; ++j) {
            int node = base + j;
            xs[wave][j][lane] = (node < n) ? x[node * 64 + lane] : 0.f;
        }
        __syncthreads();

        float accq[4], acck[4], accv[4];
        #pragma unroll
        for (int j = 0; j < 4; ++j) { accq[j] = bqv; acck[j] = bkv; accv[j] = bvv; }

        #pragma unroll
        for (int f = 0; f < 16; ++f) {
            float wq[4], wk[4], wv[4];
            #pragma unroll
            for (int u = 0; u < 4; ++u) {
                int i = 4 * f + u;
                wq[u] = WqT[i * 65 + lane];
                wk[u] = WkT[i * 65 + lane];
                wv[u] = WvT[i * 65 + lane];
            }
            #pragma unroll
            for (int j = 0; j < 4; ++j) {
                float4 xv = *reinterpret_cast<const float4*>(&xs[wave][j][4 * f]);
                accq[j] = fmaf(xv.x, wq[0], accq[j]);
                accq[j] = fmaf(xv.y, wq[1], accq[j]);
                accq[j] = fmaf(xv.z, wq[2], accq[j]);
                accq[j] = fmaf(xv.w, wq[3], accq[j]);
                acck[j] = fmaf(xv.x, wk[0], acck[j]);
                acck[j] = fmaf(xv.y, wk[1], acck[j]);
                acck[j] = fmaf(xv.z, wk[2], acck[j]);
                acck[j] = fmaf(xv.w, wk[3], acck[j]);
                accv[j] = fmaf(xv.x, wv[0], accv[j]);
                accv[j] = fmaf(xv.y, wv[1], accv[j]);
                accv[j] = fmaf(xv.z, wv[2], accv[j]);
                accv[j] = fmaf(xv.w, wv[3], accv[j]);
            }
        }

        #pragma unroll
        for (int j = 0; j < 4; ++j) {
            int node = base + j;
            if (node < n) {
                Q[node * 64 + lane] = accq[j];
                K[node * 64 + lane] = acck[j];
                V[node * 64 + lane] = accv[j];
            }
        }
        __syncthreads();
    }
}

// ---------------- Kernel 2: per-edge attention + scatter ----------------
// block 256 = 4 independent waves, no block barriers in the loop.
// 2 edges per wave per iteration (ILP), next iteration's indices + ea
// prefetched into registers. We row PINNED in 64 VGPRs via empty-asm
// (compiler was rematerializing the loads per edge at VGPR_Count=48).
__global__ __launch_bounds__(256, 4) void edge_kernel(
    const float* __restrict__ ea, const int* __restrict__ ei,
    const float* __restrict__ Q, const float* __restrict__ K,
    const float* __restrict__ V,
    const float* __restrict__ We, const float* __restrict__ be,
    float* __restrict__ out, int EG)
{
    __shared__ float eas[4][128];    // per-wave: 2 staged ea rows

    const int tid  = threadIdx.x;
    const int wave = tid >> 6;
    const int lane = tid & 63;

    // We row for output dim `lane` -> 64 pinned VGPRs
    float wr[64];
    {
        const float4* wrow = reinterpret_cast<const float4*>(We + (size_t)lane * 64);
        #pragma unroll
        for (int f = 0; f < 16; ++f) {
            float4 t4 = wrow[f];
            wr[4 * f + 0] = t4.x;
            wr[4 * f + 1] = t4.y;
            wr[4 * f + 2] = t4.z;
            wr[4 * f + 3] = t4.w;
        }
    }
    #pragma unroll
    for (int i = 0; i < 64; ++i)
        asm volatile("" : "+v"(wr[i]));   // opaque: cannot be rematerialized
    const float bias = be[lane];

    const int W    = gridDim.x * 4;
    const int wid  = blockIdx.x * 4 + __builtin_amdgcn_readfirstlane(wave);
    const int step = W * 2;
    int base = wid * 2;
    if (base >= EG) return;

    // prefetch iteration 0
    int2   nsrc = *reinterpret_cast<const int2*>(&ei[base]);
    int2   ndst = *reinterpret_cast<const int2*>(&ei[EG + base]);
    float2 nea  = *reinterpret_cast<const float2*>(&ea[(size_t)base * 64 + 2 * lane]);

    for (; base < EG; base += step) {
        const int2   srcs = nsrc;
        const int2   dsts = ndst;
        const float2 eav  = nea;

        const int nb = base + step;
        if (nb < EG) {   // prefetch next iteration (hides ~500cy under compute)
            nsrc = *reinterpret_cast<const int2*>(&ei[nb]);
            ndst = *reinterpret_cast<const int2*>(&ei[EG + nb]);
            nea  = *reinterpret_cast<const float2*>(&ea[(size_t)nb * 64 + 2 * lane]);
        }

        // stage both ea rows: lanes 0-31 -> row e0, lanes 32-63 -> row e1
        *reinterpret_cast<float2*>(&eas[wave][2 * lane]) = eav;
        __builtin_amdgcn_wave_barrier();

        // issue gathers before matvec so they overlap the FMAs
        const bool has1 = (base + 1) < EG;
        float kv0 = K[(size_t)srcs.x * 64 + lane];
        float qv0 = Q[(size_t)dsts.x * 64 + lane];
        float vv0 = V[(size_t)srcs.x * 64 + lane];
        float kv1 = 0.f, qv1 = 0.f, vv1 = 0.f;
        if (has1) {
            kv1 = K[(size_t)srcs.y * 64 + lane];
            qv1 = Q[(size_t)dsts.y * 64 + lane];
            vv1 = V[(size_t)srcs.y * 64 + lane];
        }

        // Ee[lane] for both edges; LDS reads are uniform-address broadcasts
        float acc0 = bias, acc1 = bias;
        const float4* r0 = reinterpret_cast<const float4*>(&eas[wave][0]);
        const float4* r1 = reinterpret_cast<const float4*>(&eas[wave][64]);
        #pragma unroll
        for (int f = 0; f < 16; ++f) {
            float4 a0 = r0[f];
            float4 a1 = r1[f];
            acc0 = fmaf(a0.x, wr[4 * f + 0], acc0);
            acc0 = fmaf(a0.y, wr[4 * f + 1], acc0);
            acc0 = fmaf(a0.z, wr[4 * f + 2], acc0);
            acc0 = fmaf(a0.w, wr[4 * f + 3], acc0);
            acc1 = fmaf(a1.x, wr[4 * f + 0], acc1);
            acc1 = fmaf(a1.y, wr[4 * f + 1], acc1);
            acc1 = fmaf(a1.z, wr[4 * f + 2], acc1);
            acc1 = fmaf(a1.w, wr[4 * f + 3], acc1);
        }

        // edge 0: score, clip, exp, scatter
        {
            float t = kv0 * qv0 * 0.25f * acc0;
            t += __shfl_xor(t, 1);
            t += __shfl_xor(t, 2);
            t += __shfl_xor(t, 4);
            t += __shfl_xor(t, 8);
            t = fminf(fmaxf(t, -5.f), 5.f);
            float s = __expf(t);
            atomicAdd(&out[(size_t)dsts.x * 64 + lane], vv0 * s);
        }
        // edge 1
        if (has1) {
            float t = kv1 * qv1 * 0.25f * acc1;
            t += __shfl_xor(t, 1);
            t += __shfl_xor(t, 2);
            t += __shfl_xor(t, 4);
            t += __shfl_xor(t, 8);
            t = fminf(fmaxf(t, -5.f), 5.f);
            float s = __expf(t);
            atomicAdd(&out[(size_t)dsts.y * 64 + lane], vv1 * s);
        }
        __builtin_amdgcn_wave_barrier();   // eas reused next iteration
    }
}

extern "C" void kernel_launch(void* const* d_in, const int* in_sizes, int n_in,
                              void* d_out, int out_size, void* d_ws, size_t ws_size,
                              hipStream_t stream) {
    const float* x   = (const float*)d_in[0];
    const float* ea  = (const float*)d_in[1];
    const int*   ei  = (const int*)d_in[2];
    const float* Wq  = (const float*)d_in[3];
    const float* bq  = (const float*)d_in[4];
    const float* Wk  = (const float*)d_in[5];
    const float* bk  = (const float*)d_in[6];
    const float* We  = (const float*)d_in[7];
    const float* be  = (const float*)d_in[8];
    const float* Wv  = (const float*)d_in[9];
    const float* bv  = (const float*)d_in[10];
    float* out = (float*)d_out;

    const int n  = in_sizes[0] / 64;   // 50000
    const int EG = in_sizes[1] / 64;   // 1600000

    float* Q = (float*)d_ws;
    float* K = Q + (size_t)n * 64;
    float* V = K + (size_t)n * 64;

    hipMemsetAsync(d_out, 0, (size_t)out_size * sizeof(float), stream);

    const int projGrid = (n + 15) / 16;
    proj_kernel<<<projGrid, 256, 0, stream>>>(x, Wq, bq, Wk, bk, Wv, bv,
                                              Q, K, V, n);

    const int edgeGrid = 4096;
    edge_kernel<<<edgeGrid, 256, 0, stream>>>(ea, ei, Q, K, V, We, be,
                                              out, EG);
}